// Round 7
// baseline (228.328 us; speedup 1.0000x reference)
//
#include <hip/hip_runtime.h>
#include <stdint.h>
#include <stddef.h>

typedef __bf16 bf16;
typedef __bf16 bf16x8 __attribute__((ext_vector_type(8)));
typedef __bf16 bf16x4 __attribute__((ext_vector_type(4)));
typedef short short4v __attribute__((ext_vector_type(4)));
typedef float f32x4 __attribute__((ext_vector_type(4)));

#define GAS __attribute__((address_space(1)))
#define LAS __attribute__((address_space(3)))

__device__ __forceinline__ void async_load16(const void* g, void* l) {
  __builtin_amdgcn_global_load_lds((const GAS void*)g, (LAS void*)l, 16, 0, 0);
}

// 16x16x16 bf16 MFMA. C-layout of a 16x16 MFMA == B-layout of this shape,
// so P^T feeds PV straight from registers. Host pass gets a stub.
__device__ __forceinline__ f32x4 mfma16(bf16x4 a, bf16x4 b, f32x4 c) {
#if defined(__HIP_DEVICE_COMPILE__)
#if __has_builtin(__builtin_amdgcn_mfma_f32_16x16x16bf16_1k)
  return __builtin_amdgcn_mfma_f32_16x16x16bf16_1k(
      __builtin_bit_cast(short4v, a), __builtin_bit_cast(short4v, b), c, 0, 0, 0);
#else
  f32x4 d;
  asm volatile("v_mfma_f32_16x16x16_bf16 %0, %1, %2, %3"
               : "=v"(d)
               : "v"(a), "v"(b), "v"(c));
  return d;
#endif
#else
  (void)a; (void)b;
  return c;
#endif
}

// ---------------------------------------------------------------------------
// Kernel 1: fp32 -> bf16 casts, x4 vectorized. Wq pre-scaled by 0.125*log2(e)
// so QK^T lands in the exp2 domain. Blocks >= 8192 build the RoPE cos/sin
// table rope[s][ip] (float2, 2048x32 = 512KB).
// ---------------------------------------------------------------------------
__global__ __launch_bounds__(256) void cast_all(
    const float* __restrict__ x, const float* __restrict__ Wq,
    const float* __restrict__ Wk, const float* __restrict__ Wv,
    const float* __restrict__ Wo, bf16* __restrict__ Xh,
    bf16* __restrict__ Wqkv, bf16* __restrict__ Woh,
    float2* __restrict__ rope) {
  if (blockIdx.x >= 8192) {
    // RoPE table: entry e -> s = e>>5, ip = e&31 (4 per thread, same s).
    const int e = ((blockIdx.x - 8192) * 256 + threadIdx.x) * 4;
    const int s = e >> 5, ip0 = e & 31;
#pragma unroll
    for (int r = 0; r < 4; ++r) {
      const float freq = __expf((float)(ip0 + r) * -0.2878231366242557f);
      float sn, cs;
      __sincosf((float)s * freq, &sn, &cs);
      rope[e + r] = make_float2(cs, sn);
    }
    return;
  }
  int idx = (blockIdx.x * 256 + threadIdx.x) * 4;
  const float* src;
  bf16* dst;
  float scale = 1.0f;
  if (idx < 4194304) {
    src = x + idx; dst = Xh + idx;
  } else if (idx < 7340032) {
    int j = idx - 4194304;
    if (j < 1048576) {
      src = Wq + j; scale = 0.18033688011112042f;
    } else {
      src = ((j < 2097152) ? Wk : Wv) + (j & 1048575);
    }
    dst = Wqkv + j;
  } else {
    int j = idx - 7340032;
    src = Wo + j; dst = Woh + j;
  }
  float4 v = *(const float4*)src;
  bf16x4 o;
  o[0] = (bf16)(v.x * scale); o[1] = (bf16)(v.y * scale);
  o[2] = (bf16)(v.z * scale); o[3] = (bf16)(v.w * scale);
  *(bf16x4*)dst = o;
}

// ---------------------------------------------------------------------------
// Kernel 2: QKV projection with FUSED RoPE + V-transpose epilogue.
// BK=64 + both-sides XOR swizzle in the MAIN LOOP (r18 structure, verified).
// ROUND 20: output swizzles REMOVED — attn now reads K/V fragments directly
// from global into registers, so Kh and Vt are plain linear layouts:
// Q -> Qh [bh][s][64], K -> Kh [bh][s][64], V -> Vt [bh][64][2048].
// ---------------------------------------------------------------------------
__global__ __launch_bounds__(256, 3) void gemm_qkv(
    const bf16* __restrict__ A, const bf16* __restrict__ B,
    const float2* __restrict__ rope, bf16* __restrict__ Qh,
    bf16* __restrict__ Kh, bf16* __restrict__ Vt, int K) {
  __shared__ __align__(16) bf16 As[128 * 64];
  __shared__ __align__(16) bf16 Bs[128 * 64];
  const int tid = threadIdx.x;
  const int wave = tid >> 6, lane = tid & 63;
  const int bm = blockIdx.y * 128, bn = blockIdx.x * 128;
  const int wm = (wave >> 1) * 64, wn = (wave & 1) * 64;
  const int fr = lane & 15, g = lane >> 4;
  const int sw8 = (fr & 7) * 8;  // read-side swizzle

  const int srow = tid >> 3;
  const int scol = 8 * ((tid & 7) ^ (srow & 7));
  const int ldst = wave * 512;

  f32x4 acc[4][4] = {};

  for (int kt = 0; kt < K; kt += 64) {
    __syncthreads();
#pragma unroll
    for (int s = 0; s < 4; ++s) {
      const int row = s * 32 + srow;
      async_load16(A + (size_t)(bm + row) * K + kt + scol,
                   (void*)(As + s * 2048 + ldst));
      async_load16(B + (size_t)(bn + row) * K + kt + scol,
                   (void*)(Bs + s * 2048 + ldst));
    }
    __syncthreads();

#pragma unroll
    for (int ks = 0; ks < 2; ++ks) {
      bf16x8 af[4], bfr[4];
      const int kq = (ks * 32 + g * 8) ^ sw8;
#pragma unroll
      for (int i = 0; i < 4; ++i)
        af[i] = *(const bf16x8*)&As[(wm + i * 16 + fr) * 64 + kq];
#pragma unroll
      for (int j = 0; j < 4; ++j)
        bfr[j] = *(const bf16x8*)&Bs[(wn + j * 16 + fr) * 64 + kq];
#pragma unroll
      for (int i = 0; i < 4; ++i)
#pragma unroll
        for (int j = 0; j < 4; ++j)
          acc[i][j] = __builtin_amdgcn_mfma_f32_16x16x32_bf16(af[i], bfr[j],
                                                              acc[i][j], 0, 0, 0);
    }
  }

  const int r0 = (lane >> 4) * 4, cc = lane & 15;
  const bool oddl = cc & 1;
#pragma unroll
  for (int i = 0; i < 4; ++i) {
    const int row0 = bm + wm + i * 16 + r0;
    const int b = row0 >> 11, s0 = row0 & 2047;
#pragma unroll
    for (int j = 0; j < 4; ++j) {
      const int col = bn + wn + j * 16 + cc;  // whole wave same region per j
      if (col < 2048) {
        // RoPE: pair partner is lane^1 (col 2k <-> 2k+1)
        const int hcol = col & 1023;
        const int h = hcol >> 6, d = hcol & 63;
        const int ip = d >> 1;
        const bool isK = col >= 1024;
        bf16* dst = (isK ? Kh : Qh) + ((size_t)(b * 16 + h) * 2048) * 64;
#pragma unroll
        for (int r = 0; r < 4; ++r) {
          float own = acc[i][j][r];
          float oth = __shfl_xor(own, 1, 64);
          const float2 t = rope[((s0 + r) << 5) + ip];
          float res = oddl ? (oth * t.y + own * t.x) : (own * t.x - oth * t.y);
          dst[(size_t)(s0 + r) * 64 + d] = (bf16)res;
        }
      } else {
        const int v = col - 2048, h = v >> 6, d = v & 63;
        bf16x4 o;
#pragma unroll
        for (int r = 0; r < 4; ++r) o[r] = (bf16)acc[i][j][r];
        *(bf16x4*)&Vt[(((size_t)b * 16 + h) * 64 + d) * 2048 + s0] = o;
      }
    }
  }
}

// ---------------------------------------------------------------------------
// Kernel 2b (out-proj): C(MxN) = A(MxK) @ B(NxK)^T, fp32 out.
// BK=64 + both-sides-swizzle structure (r19, unchanged).
// ---------------------------------------------------------------------------
template <typename OutT, int BM, int BN>
__global__ __launch_bounds__(256) void gemm_bt(
    const bf16* __restrict__ A, const bf16* __restrict__ B,
    OutT* __restrict__ C, int M, int N, int K) {
  constexpr int FM = BM / 32, FN = BN / 32;
  constexpr int SA = BM / 32, SB = BN / 32;
  __shared__ __align__(16) bf16 As[BM * 64];
  __shared__ __align__(16) bf16 Bs[BN * 64];
  const int tid = threadIdx.x;
  const int wave = tid >> 6, lane = tid & 63;
  const int bm = blockIdx.y * BM, bn = blockIdx.x * BN;
  const int wm = (wave >> 1) * (BM / 2), wn = (wave & 1) * (BN / 2);
  const int fr = lane & 15, g = lane >> 4;
  const int sw8 = (fr & 7) * 8;
  const int srow = tid >> 3;
  const int scol = 8 * ((tid & 7) ^ (srow & 7));
  const int ldst = wave * 512;

  f32x4 acc[FM][FN] = {};

  for (int kt = 0; kt < K; kt += 64) {
    __syncthreads();
#pragma unroll
    for (int s = 0; s < SA; ++s)
      async_load16(A + (size_t)(bm + s * 32 + srow) * K + kt + scol,
                   (void*)(As + s * 2048 + ldst));
#pragma unroll
    for (int s = 0; s < SB; ++s)
      async_load16(B + (size_t)(bn + s * 32 + srow) * K + kt + scol,
                   (void*)(Bs + s * 2048 + ldst));
    __syncthreads();

#pragma unroll
    for (int ks = 0; ks < 2; ++ks) {
      const int kq = (ks * 32 + g * 8) ^ sw8;
      bf16x8 af[FM], bfr[FN];
#pragma unroll
      for (int i = 0; i < FM; ++i)
        af[i] = *(const bf16x8*)&As[(wm + i * 16 + fr) * 64 + kq];
#pragma unroll
      for (int j = 0; j < FN; ++j)
        bfr[j] = *(const bf16x8*)&Bs[(wn + j * 16 + fr) * 64 + kq];
#pragma unroll
      for (int i = 0; i < FM; ++i)
#pragma unroll
        for (int j = 0; j < FN; ++j)
          acc[i][j] = __builtin_amdgcn_mfma_f32_16x16x32_bf16(af[i], bfr[j],
                                                              acc[i][j], 0, 0, 0);
    }
  }

  const int r0 = (lane >> 4) * 4, cc = lane & 15;
#pragma unroll
  for (int i = 0; i < FM; ++i)
#pragma unroll
    for (int j = 0; j < FN; ++j)
#pragma unroll
      for (int r = 0; r < 4; ++r)
        C[(size_t)(bm + wm + i * 16 + r0 + r) * N + (bn + wn + j * 16 + cc)] =
            (OutT)acc[i][j][r];
}

// ---------------------------------------------------------------------------
// Kernel 3: causal attention — ROUND 20: barrier-free all-register waves.
// r19 post-mortem: L2 fix worked (FETCH 55->12MB) but dur stuck ~45us at
// Occupancy 11.6% -> barrier convoy between unequal co-scheduled blocks;
// per-iter wall 3360cy vs ~700cy issue. The barriers existed only for LDS
// staging -- but K-tile (8x bf16x8) and V-tile (16x bf16x4) fragments FIT
// IN REGISTERS. So:
//   * Wave = 32 q-rows, fully independent: pk from Kh (16B/lane), av from
//     Vt d-major (8B/lane, 32B coalesced runs, L2-hot). Zero LDS, zero
//     barriers, zero swizzles, zero lgkm waits.
//   * Register prefetch 1 tile ahead (ldK/ldV mid-iter, consumed next iter
//     after vmcnt(0)): ~500cy issue-to-use >> L2 latency. av double-buffered
//     (A/B via 2x-unrolled loop body, all indices static); pk WAR handled
//     by regalloc.
//   * Equalized waves: each wave runs q-tile 63-P then q-tile P -> every
//     wave does exactly 33-34 tile-iters. Grid 256 blocks = 1/CU, uniform
//     occupancy to the end. bh = f&31 -> 4 bh per XCD (2MB, L2-fits).
// Floors: issue ~8.8us, L2 BW (550MB @ 34.5TB/s) ~16us -> predict 17-22us.
// ---------------------------------------------------------------------------
__global__ __launch_bounds__(256, 1) void attn(const bf16* __restrict__ Qh,
                                               const bf16* __restrict__ Kh,
                                               const bf16* __restrict__ Vt,
                                               bf16* __restrict__ Oh) {
  const int f = blockIdx.x;
  const int bh = f & 31;  // consecutive blocks -> XCD-affine bh
  const int tid = threadIdx.x, w = tid >> 6, lane = tid & 63;
  const int P = ((f >> 5) << 2) | w;  // 0..31, per-wave pair index
  const int nlo = lane & 15, g = lane >> 4;
  const bf16* __restrict__ Qp = Qh + (size_t)bh * 131072;
  const bf16* __restrict__ Kp = Kh + (size_t)bh * 131072;
  const bf16* __restrict__ Vp = Vt + (size_t)bh * 131072;
  const int bb = bh >> 4, hd = bh & 15;

  bf16x8 aq[2][2];
  bf16x8 pk[4][2];        // K fragments of current tile (prefetched)
  bf16x4 avA[4][4], avB[4][4];  // V fragments, double-buffered

  auto ldK = [&](int i) {
#pragma unroll
    for (int ni = 0; ni < 4; ++ni)
#pragma unroll
      for (int ks = 0; ks < 2; ++ks)
        pk[ni][ks] = *(const bf16x8*)&Kp[(size_t)(i * 64 + ni * 16 + nlo) * 64 +
                                         ks * 32 + g * 8];
  };
  auto ldV = [&](bf16x4 (&dst)[4][4], int i) {
#pragma unroll
    for (int ni = 0; ni < 4; ++ni)
#pragma unroll
      for (int mi = 0; mi < 4; ++mi)
        dst[ni][mi] = *(const bf16x4*)&Vp[(size_t)(mi * 16 + nlo) * 2048 +
                                          i * 64 + ni * 16 + g * 4];
  };

  // two sequential phases: long q-tile (63-P), then short q-tile (P)
  for (int ph = 0; ph < 2; ++ph) {
    const int qt = ph ? P : 63 - P;
    const int n = (qt >> 1) + 1;  // k-tiles for this q-tile
    const int q0 = qt * 32;

#pragma unroll
    for (int qb = 0; qb < 2; ++qb)
#pragma unroll
      for (int ks = 0; ks < 2; ++ks)
        aq[qb][ks] =
            *(const bf16x8*)&Qp[(size_t)(q0 + qb * 16 + nlo) * 64 + ks * 32 + g * 8];

    f32x4 oacc[2][4] = {};  // [qb][d-block], O^T C-layout (m=d, n=q)
    float lsum[2] = {0.f, 0.f};

    ldK(0);
    ldV(avA, 0);

    auto iter = [&](int i, bf16x4 (&avCur)[4][4], bf16x4 (&avNxt)[4][4]) {
      asm volatile("s_waitcnt vmcnt(0)" ::: "memory");  // tile-i regs landed
      // S^T = K.Q^T
      f32x4 st[2][4] = {};
#pragma unroll
      for (int qb = 0; qb < 2; ++qb)
#pragma unroll
        for (int ks = 0; ks < 2; ++ks)
#pragma unroll
          for (int ni = 0; ni < 4; ++ni)
            st[qb][ni] = __builtin_amdgcn_mfma_f32_16x16x32_bf16(
                pk[ni][ks], aq[qb][ks], st[qb][ni], 0, 0, 0);
      // prefetch tile i+1 (lands before next iter's vmcnt(0))
      if (i + 1 < n) {
        ldK(i + 1);
        ldV(avNxt, i + 1);
      }
      // p = exp2(S^T), l in-lane; mask only on the diagonal tile
      const int kbase = i * 64;
      const bool dg = (i == n - 1);  // wave-uniform
      bf16x4 p[2][4];
#pragma unroll
      for (int qb = 0; qb < 2; ++qb) {
        const int qg = q0 + qb * 16 + nlo;
        if (!dg) {
#pragma unroll
          for (int ni = 0; ni < 4; ++ni)
#pragma unroll
            for (int r = 0; r < 4; ++r) {
              float e = __builtin_amdgcn_exp2f(st[qb][ni][r]);
              lsum[qb] += e;
              p[qb][ni][r] = (bf16)e;
            }
        } else {
#pragma unroll
          for (int ni = 0; ni < 4; ++ni) {
            const int kg0 = kbase + ni * 16 + g * 4;
#pragma unroll
            for (int r = 0; r < 4; ++r) {
              float e = __builtin_amdgcn_exp2f(st[qb][ni][r]);
              e = (kg0 + r <= qg) ? e : 0.0f;
              lsum[qb] += e;
              p[qb][ni][r] = (bf16)e;
            }
          }
        }
      }
      // O^T += V^T.P
#pragma unroll
      for (int ni = 0; ni < 4; ++ni)
#pragma unroll
        for (int mi = 0; mi < 4; ++mi)
#pragma unroll
          for (int qb = 0; qb < 2; ++qb)
            oacc[qb][mi] = mfma16(avCur[ni][mi], p[qb][ni], oacc[qb][mi]);
    };

    // 2x-unrolled main loop keeps av buffer indices compile-time (rule #20)
    int i = 0;
    while (true) {
      iter(i, avA, avB);
      ++i;
      if (i >= n) break;
      iter(i, avB, avA);
      ++i;
      if (i >= n) break;
    }

    // finish l: reduce over the 4 g-groups (columns are per-nlo)
#pragma unroll
    for (int qb = 0; qb < 2; ++qb) {
      lsum[qb] += __shfl_xor(lsum[qb], 16, 64);
      lsum[qb] += __shfl_xor(lsum[qb], 32, 64);
    }

    // write this phase's 32 rows
#pragma unroll
    for (int qb = 0; qb < 2; ++qb) {
      const float inv = 1.0f / lsum[qb];
      const int q = q0 + qb * 16 + nlo;
#pragma unroll
      for (int mi = 0; mi < 4; ++mi) {
        bf16x4 o;
#pragma unroll
        for (int r = 0; r < 4; ++r) o[r] = (bf16)(oacc[qb][mi][r] * inv);
        *(bf16x4*)&Oh[((size_t)bb * 2048 + q) * 1024 + hd * 64 + mi * 16 + g * 4] = o;
      }
    }
  }
}

// ---------------------------------------------------------------------------
extern "C" void kernel_launch(void* const* d_in, const int* in_sizes, int n_in,
                              void* d_out, int out_size, void* d_ws, size_t ws_size,
                              hipStream_t stream) {
  (void)in_sizes; (void)n_in; (void)out_size; (void)ws_size;
  const float* x = (const float*)d_in[0];
  const float* Wq = (const float*)d_in[1];
  const float* Wk = (const float*)d_in[2];
  const float* Wv = (const float*)d_in[3];
  const float* Wo = (const float*)d_in[4];
  float* out = (float*)d_out;
  char* ws = (char*)d_ws;

  bf16* Xh    = (bf16*)(ws);                 // 4096x1024          8 MB
  bf16* Wqkv  = (bf16*)(ws + 8388608);       // 3072x1024          6 MB
  bf16* Woh   = (bf16*)(ws + 14680064);      // 1024x1024          2 MB
  bf16* Qh    = (bf16*)(ws + 16777216);      // [32][2048][64]     8 MB
  bf16* Kh    = (bf16*)(ws + 25165824);      // [32][2048][64]     8 MB (linear)
  bf16* Vt    = (bf16*)(ws + 33554432);      // [32][64][2048]     8 MB (linear)
  bf16* Oh    = (bf16*)(ws + 41943040);      // 4096x1024          8 MB
  float2* rope = (float2*)(ws + 50331648);   // [2048][32] cos/sin 512 KB

  cast_all<<<8256, 256, 0, stream>>>(x, Wq, Wk, Wv, Wo, Xh, Wqkv, Woh, rope);
  gemm_qkv<<<dim3(24, 32), 256, 0, stream>>>(Xh, Wqkv, rope, Qh, Kh, Vt, 1024);
  attn<<<256, 256, 0, stream>>>(Qh, Kh, Vt, Oh);
  gemm_bt<float, 128, 128><<<dim3(8, 32), 256, 0, stream>>>(Oh, Woh, out, 4096, 1024, 1024);
}

// Round 8
// 183.077 us; speedup vs baseline: 1.2472x; 1.2472x over previous
//
#include <hip/hip_runtime.h>
#include <stdint.h>
#include <stddef.h>

typedef __bf16 bf16;
typedef __bf16 bf16x8 __attribute__((ext_vector_type(8)));
typedef __bf16 bf16x4 __attribute__((ext_vector_type(4)));
typedef short short4v __attribute__((ext_vector_type(4)));
typedef float f32x4 __attribute__((ext_vector_type(4)));

#define GAS __attribute__((address_space(1)))
#define LAS __attribute__((address_space(3)))

__device__ __forceinline__ void async_load16(const void* g, void* l) {
  __builtin_amdgcn_global_load_lds((const GAS void*)g, (LAS void*)l, 16, 0, 0);
}

// 16x16x16 bf16 MFMA. C-layout of a 16x16 MFMA == B-layout of this shape,
// so P^T feeds PV straight from registers. Host pass gets a stub.
__device__ __forceinline__ f32x4 mfma16(bf16x4 a, bf16x4 b, f32x4 c) {
#if defined(__HIP_DEVICE_COMPILE__)
#if __has_builtin(__builtin_amdgcn_mfma_f32_16x16x16bf16_1k)
  return __builtin_amdgcn_mfma_f32_16x16x16bf16_1k(
      __builtin_bit_cast(short4v, a), __builtin_bit_cast(short4v, b), c, 0, 0, 0);
#else
  f32x4 d;
  asm volatile("v_mfma_f32_16x16x16_bf16 %0, %1, %2, %3"
               : "=v"(d)
               : "v"(a), "v"(b), "v"(c));
  return d;
#endif
#else
  (void)a; (void)b;
  return c;
#endif
}

// ---------------------------------------------------------------------------
// Kernel 1: fp32 -> bf16 casts, x4 vectorized. Wq pre-scaled by 0.125*log2(e)
// so QK^T lands in the exp2 domain. Blocks >= 8192 build the RoPE cos/sin
// table rope[s][ip] (float2, 2048x32 = 512KB).
// ---------------------------------------------------------------------------
__global__ __launch_bounds__(256) void cast_all(
    const float* __restrict__ x, const float* __restrict__ Wq,
    const float* __restrict__ Wk, const float* __restrict__ Wv,
    const float* __restrict__ Wo, bf16* __restrict__ Xh,
    bf16* __restrict__ Wqkv, bf16* __restrict__ Woh,
    float2* __restrict__ rope) {
  if (blockIdx.x >= 8192) {
    const int e = ((blockIdx.x - 8192) * 256 + threadIdx.x) * 4;
    const int s = e >> 5, ip0 = e & 31;
#pragma unroll
    for (int r = 0; r < 4; ++r) {
      const float freq = __expf((float)(ip0 + r) * -0.2878231366242557f);
      float sn, cs;
      __sincosf((float)s * freq, &sn, &cs);
      rope[e + r] = make_float2(cs, sn);
    }
    return;
  }
  int idx = (blockIdx.x * 256 + threadIdx.x) * 4;
  const float* src;
  bf16* dst;
  float scale = 1.0f;
  if (idx < 4194304) {
    src = x + idx; dst = Xh + idx;
  } else if (idx < 7340032) {
    int j = idx - 4194304;
    if (j < 1048576) {
      src = Wq + j; scale = 0.18033688011112042f;
    } else {
      src = ((j < 2097152) ? Wk : Wv) + (j & 1048575);
    }
    dst = Wqkv + j;
  } else {
    int j = idx - 7340032;
    src = Wo + j; dst = Woh + j;
  }
  float4 v = *(const float4*)src;
  bf16x4 o;
  o[0] = (bf16)(v.x * scale); o[1] = (bf16)(v.y * scale);
  o[2] = (bf16)(v.z * scale); o[3] = (bf16)(v.w * scale);
  *(bf16x4*)dst = o;
}

// ---------------------------------------------------------------------------
// Kernel 2: QKV projection with FUSED RoPE + V-transpose epilogue.
// BK=64 + both-sides XOR swizzle in the main loop (r18, verified).
// ROUND 21: Vt col-swizzle RESTORED (attn stages V into LDS again);
// Q -> Qh linear; K -> Kh linear (attn reads K fragments global->reg).
// ---------------------------------------------------------------------------
__global__ __launch_bounds__(256, 3) void gemm_qkv(
    const bf16* __restrict__ A, const bf16* __restrict__ B,
    const float2* __restrict__ rope, bf16* __restrict__ Qh,
    bf16* __restrict__ Kh, bf16* __restrict__ Vt, int K) {
  __shared__ __align__(16) bf16 As[128 * 64];
  __shared__ __align__(16) bf16 Bs[128 * 64];
  const int tid = threadIdx.x;
  const int wave = tid >> 6, lane = tid & 63;
  const int bm = blockIdx.y * 128, bn = blockIdx.x * 128;
  const int wm = (wave >> 1) * 64, wn = (wave & 1) * 64;
  const int fr = lane & 15, g = lane >> 4;
  const int sw8 = (fr & 7) * 8;  // read-side swizzle

  const int srow = tid >> 3;
  const int scol = 8 * ((tid & 7) ^ (srow & 7));
  const int ldst = wave * 512;

  f32x4 acc[4][4] = {};

  for (int kt = 0; kt < K; kt += 64) {
    __syncthreads();
#pragma unroll
    for (int s = 0; s < 4; ++s) {
      const int row = s * 32 + srow;
      async_load16(A + (size_t)(bm + row) * K + kt + scol,
                   (void*)(As + s * 2048 + ldst));
      async_load16(B + (size_t)(bn + row) * K + kt + scol,
                   (void*)(Bs + s * 2048 + ldst));
    }
    __syncthreads();

#pragma unroll
    for (int ks = 0; ks < 2; ++ks) {
      bf16x8 af[4], bfr[4];
      const int kq = (ks * 32 + g * 8) ^ sw8;
#pragma unroll
      for (int i = 0; i < 4; ++i)
        af[i] = *(const bf16x8*)&As[(wm + i * 16 + fr) * 64 + kq];
#pragma unroll
      for (int j = 0; j < 4; ++j)
        bfr[j] = *(const bf16x8*)&Bs[(wn + j * 16 + fr) * 64 + kq];
#pragma unroll
      for (int i = 0; i < 4; ++i)
#pragma unroll
        for (int j = 0; j < 4; ++j)
          acc[i][j] = __builtin_amdgcn_mfma_f32_16x16x32_bf16(af[i], bfr[j],
                                                              acc[i][j], 0, 0, 0);
    }
  }

  const int r0 = (lane >> 4) * 4, cc = lane & 15;
  const bool oddl = cc & 1;
#pragma unroll
  for (int i = 0; i < 4; ++i) {
    const int row0 = bm + wm + i * 16 + r0;
    const int b = row0 >> 11, s0 = row0 & 2047;
#pragma unroll
    for (int j = 0; j < 4; ++j) {
      const int col = bn + wn + j * 16 + cc;  // whole wave same region per j
      if (col < 2048) {
        // RoPE: pair partner is lane^1 (col 2k <-> 2k+1)
        const int hcol = col & 1023;
        const int h = hcol >> 6, d = hcol & 63;
        const int ip = d >> 1;
        const bool isK = col >= 1024;
        bf16* dst = (isK ? Kh : Qh) + ((size_t)(b * 16 + h) * 2048) * 64;
#pragma unroll
        for (int r = 0; r < 4; ++r) {
          float own = acc[i][j][r];
          float oth = __shfl_xor(own, 1, 64);
          const float2 t = rope[((s0 + r) << 5) + ip];
          float res = oddl ? (oth * t.y + own * t.x) : (own * t.x - oth * t.y);
          dst[(size_t)(s0 + r) * 64 + d] = (bf16)res;
        }
      } else {
        const int v = col - 2048, h = v >> 6, d = v & 63;
        bf16x4 o;
#pragma unroll
        for (int r = 0; r < 4; ++r) o[r] = (bf16)acc[i][j][r];
        // col-swizzled within each 64-wide tile (verified r18/r19); 4-run
        // at s0 stays contiguous (XOR touches bits 3..5, s0 is 4-aligned)
        const int s2 = (s0 & ~63) | ((s0 ^ ((d & 7) << 3)) & 63);
        *(bf16x4*)&Vt[(((size_t)b * 16 + h) * 64 + d) * 2048 + s2] = o;
      }
    }
  }
}

// ---------------------------------------------------------------------------
// Kernel 2b (out-proj): C(MxN) = A(MxK) @ B(NxK)^T, fp32 out.
// BK=64 + both-sides-swizzle structure (r19, unchanged).
// ---------------------------------------------------------------------------
template <typename OutT, int BM, int BN>
__global__ __launch_bounds__(256) void gemm_bt(
    const bf16* __restrict__ A, const bf16* __restrict__ B,
    OutT* __restrict__ C, int M, int N, int K) {
  constexpr int FM = BM / 32, FN = BN / 32;
  constexpr int SA = BM / 32, SB = BN / 32;
  __shared__ __align__(16) bf16 As[BM * 64];
  __shared__ __align__(16) bf16 Bs[BN * 64];
  const int tid = threadIdx.x;
  const int wave = tid >> 6, lane = tid & 63;
  const int bm = blockIdx.y * BM, bn = blockIdx.x * BN;
  const int wm = (wave >> 1) * (BM / 2), wn = (wave & 1) * (BN / 2);
  const int fr = lane & 15, g = lane >> 4;
  const int sw8 = (fr & 7) * 8;
  const int srow = tid >> 3;
  const int scol = 8 * ((tid & 7) ^ (srow & 7));
  const int ldst = wave * 512;

  f32x4 acc[FM][FN] = {};

  for (int kt = 0; kt < K; kt += 64) {
    __syncthreads();
#pragma unroll
    for (int s = 0; s < SA; ++s)
      async_load16(A + (size_t)(bm + s * 32 + srow) * K + kt + scol,
                   (void*)(As + s * 2048 + ldst));
#pragma unroll
    for (int s = 0; s < SB; ++s)
      async_load16(B + (size_t)(bn + s * 32 + srow) * K + kt + scol,
                   (void*)(Bs + s * 2048 + ldst));
    __syncthreads();

#pragma unroll
    for (int ks = 0; ks < 2; ++ks) {
      const int kq = (ks * 32 + g * 8) ^ sw8;
      bf16x8 af[FM], bfr[FN];
#pragma unroll
      for (int i = 0; i < FM; ++i)
        af[i] = *(const bf16x8*)&As[(wm + i * 16 + fr) * 64 + kq];
#pragma unroll
      for (int j = 0; j < FN; ++j)
        bfr[j] = *(const bf16x8*)&Bs[(wn + j * 16 + fr) * 64 + kq];
#pragma unroll
      for (int i = 0; i < FM; ++i)
#pragma unroll
        for (int j = 0; j < FN; ++j)
          acc[i][j] = __builtin_amdgcn_mfma_f32_16x16x32_bf16(af[i], bfr[j],
                                                              acc[i][j], 0, 0, 0);
    }
  }

  const int r0 = (lane >> 4) * 4, cc = lane & 15;
#pragma unroll
  for (int i = 0; i < FM; ++i)
#pragma unroll
    for (int j = 0; j < FN; ++j)
#pragma unroll
      for (int r = 0; r < 4; ++r)
        C[(size_t)(bm + wm + i * 16 + r0 + r) * N + (bn + wn + j * 16 + cc)] =
            (OutT)acc[i][j][r];
}

// ---------------------------------------------------------------------------
// Kernel 3: causal attention — ROUND 21: equalized 2-wave k-split blocks,
// barrier-free k-loop, 2 waves/SIMD.
// Post-mortems driving this design:
//   r20 (93us): fragment-granule global gathers fragment L2 sectors (4-5x
//     oversubscription) AND 1 wave/SIMD exposes all latency. -> V must be
//     staged via coalesced global_load_lds; K's 64B-sector reads are fine
//     direct-to-register (r14-proven).
//   r19 (44.8us): unequal barrier-synced blocks -> convoy; occupancy 11.5%
//     (long blocks ran alone half the kernel). -> all blocks EQUAL length,
//     no in-loop barriers.
// Design: 1024 blocks x 128 thr; block = 32-row q-tile pair (63-P, P) =
// exactly 33 k-iters; the 2 waves split each tile's k-range (additive
// unnormalized exp2; combine via one LDS round-trip per tile). 8 waves/CU
// = 2/SIMD. K global->reg double-buffered 1 tile ahead; V global->LDS
// (wave-private slots, pre-swizzled Vt, inverse-XOR read) double-buffered.
// Counted vmcnt only (8/16); vmcnt(0) only at tile tail.
// ---------------------------------------------------------------------------
__global__ __launch_bounds__(128, 2) void attn(const bf16* __restrict__ Qh,
                                               const bf16* __restrict__ Kh,
                                               const bf16* __restrict__ Vt,
                                               bf16* __restrict__ Oh) {
  __shared__ __align__(16) bf16 Vs[2][2][64 * 64];  // [wave][slot], 32 KB
  const int f = blockIdx.x;
  const int bh = f & 31;        // bh%8 == f%8 -> XCD affinity (4 bh/XCD)
  const int P = (f >> 5) & 31;  // tile-pair index
  const int tid = threadIdx.x, w = tid >> 6, lane = tid & 63;
  const int nlo = lane & 15, g = lane >> 4;
  const bf16* __restrict__ Qp = Qh + (size_t)bh * 131072;
  const bf16* __restrict__ Kp = Kh + (size_t)bh * 131072;
  const bf16* __restrict__ Vp = Vt + (size_t)bh * 131072;
  const int bb = bh >> 4, hd = bh & 15;
  const int sw = (nlo & 7) << 3;              // inverse XOR for V reads
  const int srow = lane >> 3, soff = (lane & 7) * 8;  // V staging geometry
  bf16* __restrict__ Vw0 = Vs[w][0];
  bf16* __restrict__ Vw1 = Vs[w][1];
  float* __restrict__ scr = (float*)Vs[1][0];  // combine scratch (wave1 slot)
  float* __restrict__ scl = (float*)Vs[1][1];  // lsum scratch

  bf16x8 pkA[4][2], pkB[4][2];  // K fragments, double-buffered

  for (int ph = 0; ph < 2; ++ph) {
    const int qt = ph ? P : 63 - P;       // long tile first
    const int q0 = qt * 32;
    const int n = (qt >> 1) + 1;          // k-tiles for this q-tile
    const int h = (n + 1) >> 1;           // wave0: [0,h), wave1: [h,n)
    const int t0 = w ? h : 0;
    const int cnt = w ? (n - h) : h;

    bf16x8 aq[2][2];
#pragma unroll
    for (int qb = 0; qb < 2; ++qb)
#pragma unroll
      for (int ks = 0; ks < 2; ++ks)
        aq[qb][ks] = *(const bf16x8*)&Qp[(size_t)(q0 + qb * 16 + nlo) * 64 +
                                         ks * 32 + g * 8];

    f32x4 oacc[2][4] = {};  // O^T C-layout (m=d, n=q)
    float lsum[2] = {0.f, 0.f};

    auto ldK = [&](bf16x8 (&pk)[4][2], int i) {
#pragma unroll
      for (int ni = 0; ni < 4; ++ni)
#pragma unroll
        for (int ks = 0; ks < 2; ++ks)
          pk[ni][ks] = *(const bf16x8*)&Kp[(size_t)(i * 64 + ni * 16 + nlo) * 64 +
                                           ks * 32 + g * 8];
    };
    auto stageV = [&](bf16* dst, int i) {
      const bf16* src = Vp + (size_t)srow * 2048 + i * 64 + soff;
#pragma unroll
      for (int c = 0; c < 8; ++c)
        async_load16(src + (size_t)c * 16384, (void*)(dst + c * 512));
    };

    auto body = [&](int it, bf16x8 (&pkC)[4][2], bf16x8 (&pkN)[4][2],
                    bf16* VwC, bf16* VwN) {
      const int i = t0 + it;
      // K(i) landed (leaves V(i)'s 8 gload_lds in flight)
      asm volatile("s_waitcnt vmcnt(8)" ::: "memory");
      f32x4 st[2][4] = {};
#pragma unroll
      for (int qb = 0; qb < 2; ++qb)
#pragma unroll
        for (int ks = 0; ks < 2; ++ks)
#pragma unroll
          for (int ni = 0; ni < 4; ++ni)
            st[qb][ni] = __builtin_amdgcn_mfma_f32_16x16x32_bf16(
                pkC[ni][ks], aq[qb][ks], st[qb][ni], 0, 0, 0);
      const bool more = (it + 1 < cnt);
      if (more) {       // prefetch tile i+1: K->regs, V->other LDS slot
        ldK(pkN, i + 1);
        stageV(VwN, i + 1);
      }
      const int kbase = i * 64;
      const bool dg = (i == n - 1);  // diagonal tile (wave-uniform)
      bf16x4 p[2][4];
#pragma unroll
      for (int qb = 0; qb < 2; ++qb) {
        const int qg = q0 + qb * 16 + nlo;
        if (!dg) {
#pragma unroll
          for (int ni = 0; ni < 4; ++ni)
#pragma unroll
            for (int r = 0; r < 4; ++r) {
              float e = __builtin_amdgcn_exp2f(st[qb][ni][r]);
              lsum[qb] += e;
              p[qb][ni][r] = (bf16)e;
            }
        } else {
#pragma unroll
          for (int ni = 0; ni < 4; ++ni) {
            const int kg0 = kbase + ni * 16 + g * 4;
#pragma unroll
            for (int r = 0; r < 4; ++r) {
              float e = __builtin_amdgcn_exp2f(st[qb][ni][r]);
              e = (kg0 + r <= qg) ? e : 0.0f;
              lsum[qb] += e;
              p[qb][ni][r] = (bf16)e;
            }
          }
        }
      }
      // V(i) landed (leaves K(i+1)+V(i+1) = 16 in flight)
      if (more)
        asm volatile("s_waitcnt vmcnt(16)" ::: "memory");
      else
        asm volatile("s_waitcnt vmcnt(0)" ::: "memory");
      // O^T += V^T.P
#pragma unroll
      for (int ni = 0; ni < 4; ++ni)
#pragma unroll
        for (int mi = 0; mi < 4; ++mi) {
          bf16x4 av = *(const bf16x4*)&VwC[(mi * 16 + nlo) * 64 +
                                           ((ni * 16 + g * 4) ^ sw)];
#pragma unroll
          for (int qb = 0; qb < 2; ++qb)
            oacc[qb][mi] = mfma16(av, p[qb][ni], oacc[qb][mi]);
        }
    };

    if (cnt > 0) {
      ldK(pkA, t0);
      stageV(Vw0, t0);
      int it = 0;
      while (true) {
        body(it, pkA, pkB, Vw0, Vw1);
        if (++it >= cnt) break;
        body(it, pkB, pkA, Vw1, Vw0);
        if (++it >= cnt) break;
      }
    }

    // finish l: reduce over the 4 g-groups (columns are per-nlo)
#pragma unroll
    for (int qb = 0; qb < 2; ++qb) {
      lsum[qb] += __shfl_xor(lsum[qb], 16, 64);
      lsum[qb] += __shfl_xor(lsum[qb], 32, 64);
    }

    // combine: wave1 -> its own (now free) LDS slots; wave0 adds + writes
    if (w == 1) {
#pragma unroll
      for (int qb = 0; qb < 2; ++qb) {
#pragma unroll
        for (int mi = 0; mi < 4; ++mi)
#pragma unroll
          for (int r = 0; r < 4; ++r)
            scr[(qb * 16 + mi * 4 + r) * 64 + lane] = oacc[qb][mi][r];
        scl[qb * 64 + lane] = lsum[qb];
      }
    }
    __syncthreads();
    if (w == 0) {
#pragma unroll
      for (int qb = 0; qb < 2; ++qb) {
        const float l = lsum[qb] + scl[qb * 64 + lane];
        const float inv = 1.0f / l;
        const int q = q0 + qb * 16 + nlo;
#pragma unroll
        for (int mi = 0; mi < 4; ++mi) {
          bf16x4 o;
#pragma unroll
          for (int r = 0; r < 4; ++r)
            o[r] = (bf16)((oacc[qb][mi][r] +
                           scr[(qb * 16 + mi * 4 + r) * 64 + lane]) * inv);
          *(bf16x4*)&Oh[((size_t)bb * 2048 + q) * 1024 + hd * 64 + mi * 16 +
                        g * 4] = o;
        }
      }
    }
    __syncthreads();  // protect scratch before next phase's staging reuses it
  }
}

// ---------------------------------------------------------------------------
extern "C" void kernel_launch(void* const* d_in, const int* in_sizes, int n_in,
                              void* d_out, int out_size, void* d_ws, size_t ws_size,
                              hipStream_t stream) {
  (void)in_sizes; (void)n_in; (void)out_size; (void)ws_size;
  const float* x = (const float*)d_in[0];
  const float* Wq = (const float*)d_in[1];
  const float* Wk = (const float*)d_in[2];
  const float* Wv = (const float*)d_in[3];
  const float* Wo = (const float*)d_in[4];
  float* out = (float*)d_out;
  char* ws = (char*)d_ws;

  bf16* Xh    = (bf16*)(ws);                 // 4096x1024          8 MB
  bf16* Wqkv  = (bf16*)(ws + 8388608);       // 3072x1024          6 MB
  bf16* Woh   = (bf16*)(ws + 14680064);      // 1024x1024          2 MB
  bf16* Qh    = (bf16*)(ws + 16777216);      // [32][2048][64]     8 MB
  bf16* Kh    = (bf16*)(ws + 25165824);      // [32][2048][64]     8 MB (linear)
  bf16* Vt    = (bf16*)(ws + 33554432);      // [32][64][2048]     8 MB (col-swizzled)
  bf16* Oh    = (bf16*)(ws + 41943040);      // 4096x1024          8 MB
  float2* rope = (float2*)(ws + 50331648);   // [2048][32] cos/sin 512 KB

  cast_all<<<8256, 256, 0, stream>>>(x, Wq, Wk, Wv, Wo, Xh, Wqkv, Woh, rope);
  gemm_qkv<<<dim3(24, 32), 256, 0, stream>>>(Xh, Wqkv, rope, Qh, Kh, Vt, 1024);
  attn<<<1024, 128, 0, stream>>>(Qh, Kh, Vt, Oh);
  gemm_bt<float, 128, 128><<<dim3(8, 32), 256, 0, stream>>>(Oh, Woh, out, 4096, 1024, 1024);
}